// Round 8
// baseline (677.741 us; speedup 1.0000x reference)
//
#include <hip/hip_runtime.h>
#include <math.h>

#define NN 50000
#define EE 800000
#define FIN 256
#define HH 4
#define CC 128
#define HC 512   // HH*CC
#define VV 3

// bucketed CSR build
#define NB 196    // buckets: dst >> 8
#define SPB 256   // nodes per bucket
#define CAP 4608  // max edges per bucket (mean 4096, +8 sigma)
#define EPB 2048  // edges per phase-1 block (small => high occupancy)

typedef __attribute__((ext_vector_type(8))) short short8;
typedef __attribute__((ext_vector_type(4))) float f32x4;
typedef __attribute__((ext_vector_type(2))) float f32x2;

__device__ __forceinline__ unsigned short f2bf(float f){
  unsigned u = __float_as_uint(f);
  u += 0x7fffu + ((u >> 16) & 1);   // round-to-nearest-even
  return (unsigned short)(u >> 16);
}
__device__ __forceinline__ float bf2f(short b){
  return __uint_as_float(((unsigned)b & 0xffffu) << 16);
}

__device__ __forceinline__ float wave_sum64(float v){
#pragma unroll
  for (int off = 32; off; off >>= 1) v += __shfl_xor(v, off);
  return v;
}

// ---------------- casts ------------------------------------------------------
__global__ __launch_bounds__(256) void cast_x(const float* __restrict__ x,
                                              unsigned short* __restrict__ xb){
  int t = blockIdx.x * 256 + threadIdx.x;      // one thread per 4 elements
  float4 v = *(const float4*)&x[(size_t)t * 4];
  ushort4 o;
  o.x = f2bf(v.x); o.y = f2bf(v.y); o.z = f2bf(v.z); o.w = f2bf(v.w);
  *(ushort4*)&xb[(size_t)t * 4] = o;
}

// W is [VV][FIN][HC] fp32 -> wp[v] layout [FIN/32][HC][32] bf16
__global__ __launch_bounds__(256) void prep_w_all(const float* __restrict__ W,
                                                  unsigned short* __restrict__ wp){
  int t = blockIdx.x * 256 + threadIdx.x;      // VV*131072 threads
  int v = t >> 17;                              // FIN*HC = 131072 = 2^17
  int tl = t & 131071;
  int k = tl >> 9, n = tl & 511;
  wp[(size_t)v * (FIN * HC) + (size_t)(k >> 5) * (HC * 32) + n * 32 + (k & 31)] = f2bf(W[t]);
}

// ---------------- MFMA GEMM + fused attention scores (LDS-free) --------------
// grid (391, 4 heads, 3 views). Fragments loaded straight from global (A rows
// coalesced 64B/row; B is L2-resident in fragment-native wp layout). No K-loop
// barriers. h stored fp8 e4m3.
__global__ __launch_bounds__(256) void gemm_mfma_scores(
    const unsigned short* __restrict__ xb, const unsigned short* __restrict__ wp_all,
    unsigned char* __restrict__ hb_all,
    const float* __restrict__ a_src, const float* __restrict__ a_dst,
    float* __restrict__ ssrc_all, float* __restrict__ sdst_all){
  __shared__ float sred[2][128][2];
  int tid = threadIdx.x;
  int wave = tid >> 6, lane = tid & 63;
  int l16 = lane & 15, q = lane >> 4;
  int wr = wave >> 1, wc = wave & 1;
  int head = blockIdx.y, v = blockIdx.z;
  int rowBase = blockIdx.x * 128, colBase = head * 128;

  const unsigned short* wp = wp_all + (size_t)v * FIN * HC;
  unsigned char* hb = hb_all + (size_t)v * NN * HC;
  const float* a_src_v = a_src + v * HH * CC;
  const float* a_dst_v = a_dst + v * HH * CC;
  float* ssrc = ssrc_all + (size_t)v * NN * HH;
  float* sdst = sdst_all + (size_t)v * NN * HH;

  const unsigned short* ap[4];
  const unsigned short* bp[4];
#pragma unroll
  for (int i = 0; i < 4; i++){
    int row = min(rowBase + wr * 64 + i * 16 + l16, NN - 1);
    ap[i] = xb + (size_t)row * FIN + q * 8;
  }
#pragma unroll
  for (int j = 0; j < 4; j++){
    int col = colBase + wc * 64 + j * 16 + l16;
    bp[j] = wp + (size_t)col * 32 + q * 8;
  }
  short8 af[2][4], bf[2][4];
#pragma unroll
  for (int i = 0; i < 4; i++){
    af[0][i] = *(const short8*)(ap[i]);
    bf[0][i] = *(const short8*)(bp[i]);
  }
  f32x4 acc[4][4] = {};
#pragma unroll
  for (int kt = 0; kt < 8; kt++){
    int cur = kt & 1, nxt = cur ^ 1;
    if (kt < 7){
#pragma unroll
      for (int i = 0; i < 4; i++){
        af[nxt][i] = *(const short8*)(ap[i] + (kt + 1) * 32);
        bf[nxt][i] = *(const short8*)(bp[i] + (size_t)(kt + 1) * (HC * 32));
      }
    }
#pragma unroll
    for (int i = 0; i < 4; i++)
#pragma unroll
      for (int j = 0; j < 4; j++)
        acc[i][j] = __builtin_amdgcn_mfma_f32_16x16x32_bf16(af[cur][i], bf[cur][j], acc[i][j], 0, 0, 0);
  }
  // epilogue 1: store hb as fp8. D layout: row=(lane>>4)*4+reg, col=lane&15
#pragma unroll
  for (int i = 0; i < 4; i++){
#pragma unroll
    for (int r = 0; r < 4; r++){
      int row = rowBase + wr * 64 + i * 16 + q * 4 + r;
      if (row < NN){
        int p01 = __builtin_amdgcn_cvt_pk_fp8_f32(acc[i][0][r], acc[i][1][r], 0, false);
        int p23 = __builtin_amdgcn_cvt_pk_fp8_f32(acc[i][2][r], acc[i][3][r], 0, false);
        size_t rb = (size_t)row * HC + colBase + wc * 64 + l16;
        hb[rb +  0] = (unsigned char)(p01 & 0xff);
        hb[rb + 16] = (unsigned char)((p01 >> 8) & 0xff);
        hb[rb + 32] = (unsigned char)(p23 & 0xff);
        hb[rb + 48] = (unsigned char)((p23 >> 8) & 0xff);
      }
    }
  }
  // epilogue 2: fused scores
  float asv[4], adv[4];
#pragma unroll
  for (int j = 0; j < 4; j++){
    int c = wc * 64 + j * 16 + l16;
    asv[j] = a_src_v[head * CC + c];
    adv[j] = a_dst_v[head * CC + c];
  }
  float ps[4][4], pd[4][4];
#pragma unroll
  for (int i = 0; i < 4; i++)
#pragma unroll
    for (int r = 0; r < 4; r++){
      float s = 0.f, d = 0.f;
#pragma unroll
      for (int j = 0; j < 4; j++){
        s = fmaf(acc[i][j][r], asv[j], s);
        d = fmaf(acc[i][j][r], adv[j], d);
      }
      ps[i][r] = s; pd[i][r] = d;
    }
#pragma unroll
  for (int off = 1; off < 16; off <<= 1)
#pragma unroll
    for (int i = 0; i < 4; i++)
#pragma unroll
      for (int r = 0; r < 4; r++){
        ps[i][r] += __shfl_xor(ps[i][r], off);
        pd[i][r] += __shfl_xor(pd[i][r], off);
      }
  if (l16 == 0){
#pragma unroll
    for (int i = 0; i < 4; i++)
#pragma unroll
      for (int r = 0; r < 4; r++){
        int rl = wr * 64 + i * 16 + q * 4 + r;
        sred[wc][rl][0] = ps[i][r];
        sred[wc][rl][1] = pd[i][r];
      }
  }
  __syncthreads();
  if (tid < 128){
    int row = rowBase + tid;
    if (row < NN){
      ssrc[row * HH + head] = sred[0][tid][0] + sred[1][tid][0];
      sdst[row * HH + head] = sred[0][tid][1] + sred[1][tid][1];
    }
  }
}

// ---------------- bucketed CSR build -----------------------------------------
__global__ __launch_bounds__(256) void bucket_scatter(const int* __restrict__ e0,
    const int* __restrict__ e1, const int* __restrict__ e2,
    int* __restrict__ gcur, unsigned* __restrict__ pairs){
  int v = blockIdx.y;
  const int* ei = (v == 0) ? e0 : ((v == 1) ? e1 : e2);
  __shared__ int cnt[NB];
  __shared__ int base[NB];
  int tid = threadIdx.x;
  for (int i = tid; i < NB; i += 256) cnt[i] = 0;
  __syncthreads();
  int estart = blockIdx.x * EPB;
  int eend = min(estart + EPB, EE);
  for (int e = estart + tid; e < eend; e += 256)
    atomicAdd(&cnt[ei[EE + e] >> 8], 1);
  __syncthreads();
  for (int i = tid; i < NB; i += 256){
    int c = cnt[i];
    base[i] = (c > 0) ? atomicAdd(&gcur[v * NB + i], c) : 0;
    cnt[i] = 0;
  }
  __syncthreads();
  for (int e = estart + tid; e < eend; e += 256){
    int s = ei[e], d = ei[EE + e];
    int b = d >> 8;
    int off = base[b] + atomicAdd(&cnt[b], 1);
    if (off < CAP)
      pairs[(size_t)(v * NB + b) * CAP + off] = ((unsigned)(d & 255) << 16) | (unsigned)s;
  }
}

__global__ __launch_bounds__(256) void bucket_scan(const int* __restrict__ gcur,
                                                   int* __restrict__ bbase){
  int v = blockIdx.x;
  __shared__ int wsum[4];
  int tid = threadIdx.x, lane = tid & 63, wv = tid >> 6;
  int val = 0;
  if (tid < NB) val = min(gcur[v * NB + tid], CAP) + min(SPB, NN - tid * SPB);
  int x = val;
#pragma unroll
  for (int off = 1; off < 64; off <<= 1){
    int t = __shfl_up(x, off);
    if (lane >= off) x += t;
  }
  if (lane == 63) wsum[wv] = x;
  __syncthreads();
  int pre = 0;
#pragma unroll
  for (int w = 0; w < 4; w++) if (w < wv) pre += wsum[w];
  if (tid < NB) bbase[v * NB + tid] = pre + x - val;
}

// colx stores src*4 (pre-scaled for aggregate addressing)
__global__ __launch_bounds__(256) void bucket_csr(const int* __restrict__ gcur,
    const int* __restrict__ bbase, const unsigned* __restrict__ pairs,
    int* __restrict__ rowptr_all, int* __restrict__ colx_all){
  int v = blockIdx.y, b = blockIdx.x;
  int* rowptr = rowptr_all + v * (NN + 1);
  int* colx = colx_all + (size_t)v * (EE + NN);
  __shared__ int hist[SPB];
  __shared__ int wsum[4];
  __shared__ int lcol[CAP + SPB];
  int tid = threadIdx.x, lane = tid & 63, wv = tid >> 6;
  int node0 = b << 8;
  int nvalid = min(SPB, NN - node0);
  int cnt = min(gcur[v * NB + b], CAP);
  int base = bbase[v * NB + b];
  const unsigned* pp = pairs + (size_t)(v * NB + b) * CAP;
  hist[tid] = (tid < nvalid) ? 1 : 0;   // self loop
  __syncthreads();
  for (int i = tid; i < cnt; i += 256)
    atomicAdd(&hist[pp[i] >> 16], 1);
  __syncthreads();
  int val = hist[tid];
  int x = val;
#pragma unroll
  for (int off = 1; off < 64; off <<= 1){
    int t = __shfl_up(x, off);
    if (lane >= off) x += t;
  }
  if (lane == 63) wsum[wv] = x;
  __syncthreads();
  int pre = 0;
#pragma unroll
  for (int w = 0; w < 4; w++) if (w < wv) pre += wsum[w];
  int excl = pre + x - val;
  __syncthreads();
  hist[tid] = excl + ((tid < nvalid) ? 1 : 0);   // cursor past self loop
  if (tid < nvalid){
    rowptr[node0 + tid] = base + excl;
    lcol[excl] = (node0 + tid) << 2;              // self loop first, pre-x4
  }
  __syncthreads();
  for (int i = tid; i < cnt; i += 256){
    unsigned p = pp[i];
    int pos = atomicAdd(&hist[p >> 16], 1);
    lcol[pos] = (int)(p & 0xffffu) << 2;          // pre-x4
  }
  __syncthreads();
  int total = cnt + nvalid;
  for (int i = tid; i < total; i += 256) colx[base + i] = lcol[i];
  if (b == NB - 1 && tid == 0) rowptr[NN] = base + total;
}

// ---------------- per-dst softmax + aggregate --------------------------------
// R6 structure (64 lanes per edge, uint2 8B/lane, 8-deep prefetch) + pk-fma
// f32x2 accumulate + pre-x4 colx. One wave per (node, view).
__global__ __launch_bounds__(256) void aggregate(const unsigned char* __restrict__ hb_all,
    const float* __restrict__ ssrc_all, const float* __restrict__ sdst_all,
    const int* __restrict__ rowptr_all, const int* __restrict__ colx_all,
    const float* __restrict__ bb, unsigned short* __restrict__ vout_all){
  int v = blockIdx.y;
  const unsigned char* hb = hb_all + (size_t)v * NN * HC;
  const float* ssrc = ssrc_all + (size_t)v * NN * HH;
  const float* sdst = sdst_all + (size_t)v * NN * HH;
  const int* rowptr = rowptr_all + v * (NN + 1);
  const int* colx = colx_all + (size_t)v * (EE + NN);

  int wave = threadIdx.x >> 6, lane = threadIdx.x & 63;
  int node = blockIdx.x * 4 + wave;
  int start = rowptr[node];
  int deg = rowptr[node + 1] - start;
  int myh = lane >> 4;
  int l8 = lane * 8;
  float sdh = sdst[node * HH + myh];
  f32x2 acc2[4] = {};
  float dsum = 0.f;
  int cpre = (lane < deg) ? colx[start + lane] : 0;   // src*4
  uint2 h0, h1, h2, h3, h4, h5, h6, h7;
  float s0, s1, s2, s3, s4, s5, s6, s7;
#define AGG_PRO(HP, SP, P) { \
    int sp4 = __shfl(cpre, min(P, deg - 1)); \
    HP = *(const uint2*)&hb[((size_t)(unsigned)sp4 << 7) + l8]; \
    SP = ssrc[sp4 + myh]; }
  AGG_PRO(h0, s0, 0) AGG_PRO(h1, s1, 1) AGG_PRO(h2, s2, 2) AGG_PRO(h3, s3, 3)
  AGG_PRO(h4, s4, 4) AGG_PRO(h5, s5, 5) AGG_PRO(h6, s6, 6) AGG_PRO(h7, s7, 7)
#undef AGG_PRO
#define AGG_FMA(CH, E2) { \
    acc2[0] = __builtin_elementwise_fma(E2, __builtin_amdgcn_cvt_pk_f32_fp8(CH.x, false), acc2[0]); \
    acc2[1] = __builtin_elementwise_fma(E2, __builtin_amdgcn_cvt_pk_f32_fp8(CH.x, true),  acc2[1]); \
    acc2[2] = __builtin_elementwise_fma(E2, __builtin_amdgcn_cvt_pk_f32_fp8(CH.y, false), acc2[2]); \
    acc2[3] = __builtin_elementwise_fma(E2, __builtin_amdgcn_cvt_pk_f32_fp8(CH.y, true),  acc2[3]); }
#define AGG_STEP(HP, SP, P) { \
    float xx = SP + sdh; \
    float ce = __expf(fmaxf(xx, 0.2f * xx)); \
    dsum += ce; \
    uint2 ch = HP; \
    int ni = i + 8 + P; \
    if (ni < deg){ \
      int sp4; \
      if (ni < 64) sp4 = __shfl(cpre, ni); else sp4 = colx[start + ni]; \
      HP = *(const uint2*)&hb[((size_t)(unsigned)sp4 << 7) + l8]; \
      SP = ssrc[sp4 + myh]; \
    } \
    f32x2 e2 = {ce, ce}; \
    AGG_FMA(ch, e2) }
#define AGG_TAIL(HP, SP, P) if (rem > P){ \
    float xx = SP + sdh; \
    float ce = __expf(fmaxf(xx, 0.2f * xx)); \
    dsum += ce; \
    f32x2 e2 = {ce, ce}; \
    AGG_FMA(HP, e2) }
  int i = 0;
  for (; i + 8 <= deg; i += 8){
    AGG_STEP(h0, s0, 0) AGG_STEP(h1, s1, 1) AGG_STEP(h2, s2, 2) AGG_STEP(h3, s3, 3)
    AGG_STEP(h4, s4, 4) AGG_STEP(h5, s5, 5) AGG_STEP(h6, s6, 6) AGG_STEP(h7, s7, 7)
  }
  int rem = deg - i;
  AGG_TAIL(h0, s0, 0) AGG_TAIL(h1, s1, 1) AGG_TAIL(h2, s2, 2) AGG_TAIL(h3, s3, 3)
  AGG_TAIL(h4, s4, 4) AGG_TAIL(h5, s5, 5) AGG_TAIL(h6, s6, 6)
#undef AGG_STEP
#undef AGG_TAIL
#undef AGG_FMA
  // normalize per head + 0.25 head-mean factor, butterfly over heads
  float rinv = 0.25f / fmaxf(dsum, 1e-16f);
  float accs[8];
#pragma unroll
  for (int j = 0; j < 4; j++){
    accs[2 * j]     = acc2[j][0] * rinv;
    accs[2 * j + 1] = acc2[j][1] * rinv;
  }
#pragma unroll
  for (int off = 16; off < 64; off <<= 1){
#pragma unroll
    for (int j = 0; j < 8; j++) accs[j] += __shfl_xor(accs[j], off);
  }
  if (lane < 16){
    const float* bv = bb + v * CC;
    unsigned short* voutv = vout_all + (size_t)v * NN * CC;
    int c0 = lane * 8;
    short8 o;
#pragma unroll
    for (int j = 0; j < 8; j++){
      float vv = accs[j] + bv[c0 + j];
      float e = vv > 0.f ? vv : (__expf(vv) - 1.f);
      o[j] = (short)f2bf(e);
    }
    *(short8*)&voutv[(size_t)node * CC + c0] = o;
  }
}

// ---------------- view fusion + classifier (persistent blocks) ---------------
// 1563 blocks x 8 node-groups: sw1 (32KB) preloaded ONCE per block.
__global__ __launch_bounds__(256) void fuse_classify(const unsigned short* __restrict__ vb,
    const float* __restrict__ fw, const float* __restrict__ fb,
    const float* __restrict__ w1, const float* __restrict__ b1,
    const float* __restrict__ w2, const float* __restrict__ b2,
    float* __restrict__ out){
  __shared__ float sw1[CC * 64];
  __shared__ float sfused[4][CC];
  int tid = threadIdx.x;
  for (int i = tid * 4; i < CC * 64; i += 1024)
    *(float4*)&sw1[i] = *(const float4*)&w1[i];
  __syncthreads();
  int wave = tid >> 6, lane = tid & 63;
  float fwa = fw[lane * 2], fwb = fw[lane * 2 + 1];
  float w2a = w2[lane * 2], w2b = w2[lane * 2 + 1];
  float b1l = b1[lane];
  for (int g = 0; g < 8; g++){
    int node = blockIdx.x * 32 + g * 4 + wave;
    if (node < NN){
      unsigned r0 = *(const unsigned*)&vb[(size_t)(0 * NN + node) * CC + lane * 2];
      unsigned r1 = *(const unsigned*)&vb[(size_t)(1 * NN + node) * CC + lane * 2];
      unsigned r2 = *(const unsigned*)&vb[(size_t)(2 * NN + node) * CC + lane * 2];
      float v0x = bf2f((short)(r0 & 0xffffu)), v0y = bf2f((short)(r0 >> 16));
      float v1x = bf2f((short)(r1 & 0xffffu)), v1y = bf2f((short)(r1 >> 16));
      float v2x = bf2f((short)(r2 & 0xffffu)), v2y = bf2f((short)(r2 >> 16));
      float s0 = wave_sum64(v0x * fwa + v0y * fwb) + fb[0];
      float s1 = wave_sum64(v1x * fwa + v1y * fwb) + fb[0];
      float s2 = wave_sum64(v2x * fwa + v2y * fwb) + fb[0];
      float mx = fmaxf(s0, fmaxf(s1, s2));
      float e0 = __expf(s0 - mx), e1 = __expf(s1 - mx), e2 = __expf(s2 - mx);
      float rs = 1.f / (e0 + e1 + e2);
      float w0 = e0 * rs, w1v = e1 * rs, w2v = e2 * rs;
      float f0 = w0 * v0x + w1v * v1x + w2v * v2x;
      float f1 = w0 * v0y + w1v * v1y + w2v * v2y;
      sfused[wave][lane * 2]     = f0;
      sfused[wave][lane * 2 + 1] = f1;
      if (lane < 3){
        float wv = (lane == 0) ? w0 : ((lane == 1) ? w1v : w2v);
        out[2 * NN + node * 3 + lane] = wv;
      }
      __builtin_amdgcn_s_waitcnt(0);   // drain LDS writes (wave-local use)
      float hc = b1l;
#pragma unroll 8
      for (int c = 0; c < CC; c++)
        hc = fmaf(sfused[wave][c], sw1[c * 64 + lane], hc);
      hc = fmaxf(hc, 0.f);
      float l0 = wave_sum64(hc * w2a);
      float l1 = wave_sum64(hc * w2b);
      if (lane == 0){
        out[node * 2]     = l0 + b2[0];
        out[node * 2 + 1] = l1 + b2[1];
      }
    }
  }
}

// ---------------- launch -----------------------------------------------------
extern "C" void kernel_launch(void* const* d_in, const int* in_sizes, int n_in,
                              void* d_out, int out_size, void* d_ws, size_t ws_size,
                              hipStream_t stream){
  const float* x      = (const float*)d_in[0];
  const int*   e0     = (const int*)d_in[1];
  const int*   e1     = (const int*)d_in[2];
  const int*   e2     = (const int*)d_in[3];
  const float* W      = (const float*)d_in[4];
  const float* a_src  = (const float*)d_in[5];
  const float* a_dst  = (const float*)d_in[6];
  const float* bb     = (const float*)d_in[7];
  const float* fus_w  = (const float*)d_in[8];
  const float* fus_b  = (const float*)d_in[9];
  const float* cls_w1 = (const float*)d_in[10];
  const float* cls_b1 = (const float*)d_in[11];
  const float* cls_w2 = (const float*)d_in[12];
  const float* cls_b2 = (const float*)d_in[13];
  float* out = (float*)d_out;

  // workspace layout (~157 MB). pairs (early) and vout (late) alias.
  unsigned short* xb = (unsigned short*)d_ws;                   // NN*FIN bf16
  unsigned char* hb  = (unsigned char*)(xb + (size_t)NN * FIN); // VV*NN*HC fp8
  unsigned short* wp = (unsigned short*)(hb + (size_t)VV * NN * HC); // VV*FIN*HC bf16
  float* ssrc = (float*)(wp + (size_t)VV * FIN * HC);           // VV*NN*HH
  float* sdst = ssrc + (size_t)VV * NN * HH;                    // VV*NN*HH
  int* gcur   = (int*)(sdst + (size_t)VV * NN * HH);            // VV*NB
  int* bbase  = gcur + VV * NB;                                 // VV*NB
  int* rowptr = bbase + VV * NB;                                // VV*(NN+1)
  int* colx   = rowptr + VV * (NN + 1);                         // VV*(EE+NN)
  unsigned* pairs = (unsigned*)(colx + (size_t)VV * (EE + NN)); // VV*NB*CAP (early)
  unsigned short* voutb = (unsigned short*)pairs;               // VV*NN*CC bf16 (late)

  hipMemsetAsync(gcur, 0, (size_t)VV * NB * sizeof(int), stream);
  cast_x<<<12500, 256, 0, stream>>>(x, xb);
  prep_w_all<<<1536, 256, 0, stream>>>(W, wp);
  dim3 p1grid((EE + EPB - 1) / EPB, 3);   // 391 x 3
  bucket_scatter<<<p1grid, 256, 0, stream>>>(e0, e1, e2, gcur, pairs);
  bucket_scan<<<3, 256, 0, stream>>>(gcur, bbase);
  dim3 p2grid(NB, 3);
  bucket_csr<<<p2grid, 256, 0, stream>>>(gcur, bbase, pairs, rowptr, colx);

  dim3 ggrid(391, 4, 3);
  gemm_mfma_scores<<<ggrid, 256, 0, stream>>>(xb, wp, hb, a_src, a_dst, ssrc, sdst);
  dim3 agrid(12500, 3);
  aggregate<<<agrid, 256, 0, stream>>>(hb, ssrc, sdst, rowptr, colx, bb, voutb);
  fuse_classify<<<1563, 256, 0, stream>>>(voutb, fus_w, fus_b, cls_w1, cls_b1,
                                          cls_w2, cls_b2, out);
}

// Round 9
// 582.449 us; speedup vs baseline: 1.1636x; 1.1636x over previous
//
#include <hip/hip_runtime.h>
#include <math.h>

#define NN 50000
#define EE 800000
#define FIN 256
#define HH 4
#define CC 128
#define HC 512   // HH*CC
#define VV 3

// bucketed CSR build
#define NB 196    // buckets: dst >> 8
#define SPB 256   // nodes per bucket
#define CAP 4608  // max edges per bucket (mean 4096, +8 sigma)
#define EPB 2048  // edges per phase-1 block (small => high occupancy)

typedef __attribute__((ext_vector_type(8))) short short8;
typedef __attribute__((ext_vector_type(4))) float f32x4;
typedef __attribute__((ext_vector_type(2))) float f32x2;

__device__ __forceinline__ float lrelu(float x){ return x > 0.f ? x : 0.2f*x; }

__device__ __forceinline__ unsigned short f2bf(float f){
  unsigned u = __float_as_uint(f);
  u += 0x7fffu + ((u >> 16) & 1);   // round-to-nearest-even
  return (unsigned short)(u >> 16);
}
__device__ __forceinline__ float bf2f(short b){
  return __uint_as_float(((unsigned)b & 0xffffu) << 16);
}

__device__ __forceinline__ float wave_sum64(float v){
#pragma unroll
  for (int off = 32; off; off >>= 1) v += __shfl_xor(v, off);
  return v;
}

// ---------------- casts ------------------------------------------------------
__global__ __launch_bounds__(256) void cast_x(const float* __restrict__ x,
                                              unsigned short* __restrict__ xb){
  int t = blockIdx.x * 256 + threadIdx.x;      // one thread per 4 elements
  float4 v = *(const float4*)&x[(size_t)t * 4];
  ushort4 o;
  o.x = f2bf(v.x); o.y = f2bf(v.y); o.z = f2bf(v.z); o.w = f2bf(v.w);
  *(ushort4*)&xb[(size_t)t * 4] = o;
}

// W is [VV][FIN][HC] fp32 -> wp[v] layout [FIN/32][HC][32] bf16
__global__ __launch_bounds__(256) void prep_w_all(const float* __restrict__ W,
                                                  unsigned short* __restrict__ wp){
  int t = blockIdx.x * 256 + threadIdx.x;      // VV*131072 threads
  int v = t >> 17;                              // FIN*HC = 131072 = 2^17
  int tl = t & 131071;
  int k = tl >> 9, n = tl & 511;
  wp[(size_t)v * (FIN * HC) + (size_t)(k >> 5) * (HC * 32) + n * 32 + (k & 31)] = f2bf(W[t]);
}

// ---------------- MFMA GEMM + fused attention scores (LDS-free) --------------
// grid (391, 4 heads, 3 views). Fragments loaded straight from global, SINGLE
// buffered (minimize unified VGPR/AGPR footprint -> max waves/SIMD; cross-wave
// overlap hides load latency per m114). h stored fp8 e4m3.
__global__ __launch_bounds__(256) void gemm_mfma_scores(
    const unsigned short* __restrict__ xb, const unsigned short* __restrict__ wp_all,
    unsigned char* __restrict__ hb_all,
    const float* __restrict__ a_src, const float* __restrict__ a_dst,
    float* __restrict__ ssrc_all, float* __restrict__ sdst_all){
  __shared__ float sred[2][128][2];
  int tid = threadIdx.x;
  int wave = tid >> 6, lane = tid & 63;
  int l16 = lane & 15, q = lane >> 4;
  int wr = wave >> 1, wc = wave & 1;
  int head = blockIdx.y, v = blockIdx.z;
  int rowBase = blockIdx.x * 128, colBase = head * 128;

  const unsigned short* wp = wp_all + (size_t)v * FIN * HC;
  unsigned char* hb = hb_all + (size_t)v * NN * HC;
  const float* a_src_v = a_src + v * HH * CC;
  const float* a_dst_v = a_dst + v * HH * CC;
  float* ssrc = ssrc_all + (size_t)v * NN * HH;
  float* sdst = sdst_all + (size_t)v * NN * HH;

  const unsigned short* ap[4];
  const unsigned short* bp[4];
#pragma unroll
  for (int i = 0; i < 4; i++){
    int row = min(rowBase + wr * 64 + i * 16 + l16, NN - 1);
    ap[i] = xb + (size_t)row * FIN + q * 8;
  }
#pragma unroll
  for (int j = 0; j < 4; j++){
    int col = colBase + wc * 64 + j * 16 + l16;
    bp[j] = wp + (size_t)col * 32 + q * 8;
  }
  f32x4 acc[4][4] = {};
#pragma unroll
  for (int kt = 0; kt < 8; kt++){
    short8 af[4], bf[4];
#pragma unroll
    for (int i = 0; i < 4; i++){
      af[i] = *(const short8*)(ap[i] + kt * 32);
      bf[i] = *(const short8*)(bp[i] + (size_t)kt * (HC * 32));
    }
#pragma unroll
    for (int i = 0; i < 4; i++)
#pragma unroll
      for (int j = 0; j < 4; j++)
        acc[i][j] = __builtin_amdgcn_mfma_f32_16x16x32_bf16(af[i], bf[j], acc[i][j], 0, 0, 0);
  }
  // epilogue 1: store hb as fp8. D layout: row=(lane>>4)*4+reg, col=lane&15
#pragma unroll
  for (int i = 0; i < 4; i++){
#pragma unroll
    for (int r = 0; r < 4; r++){
      int row = rowBase + wr * 64 + i * 16 + q * 4 + r;
      if (row < NN){
        int p01 = __builtin_amdgcn_cvt_pk_fp8_f32(acc[i][0][r], acc[i][1][r], 0, false);
        int p23 = __builtin_amdgcn_cvt_pk_fp8_f32(acc[i][2][r], acc[i][3][r], 0, false);
        size_t rb = (size_t)row * HC + colBase + wc * 64 + l16;
        hb[rb +  0] = (unsigned char)(p01 & 0xff);
        hb[rb + 16] = (unsigned char)((p01 >> 8) & 0xff);
        hb[rb + 32] = (unsigned char)(p23 & 0xff);
        hb[rb + 48] = (unsigned char)((p23 >> 8) & 0xff);
      }
    }
  }
  // epilogue 2: fused scores
  float asv[4], adv[4];
#pragma unroll
  for (int j = 0; j < 4; j++){
    int c = wc * 64 + j * 16 + l16;
    asv[j] = a_src_v[head * CC + c];
    adv[j] = a_dst_v[head * CC + c];
  }
  float ps[4][4], pd[4][4];
#pragma unroll
  for (int i = 0; i < 4; i++)
#pragma unroll
    for (int r = 0; r < 4; r++){
      float s = 0.f, d = 0.f;
#pragma unroll
      for (int j = 0; j < 4; j++){
        s = fmaf(acc[i][j][r], asv[j], s);
        d = fmaf(acc[i][j][r], adv[j], d);
      }
      ps[i][r] = s; pd[i][r] = d;
    }
#pragma unroll
  for (int off = 1; off < 16; off <<= 1)
#pragma unroll
    for (int i = 0; i < 4; i++)
#pragma unroll
      for (int r = 0; r < 4; r++){
        ps[i][r] += __shfl_xor(ps[i][r], off);
        pd[i][r] += __shfl_xor(pd[i][r], off);
      }
  if (l16 == 0){
#pragma unroll
    for (int i = 0; i < 4; i++)
#pragma unroll
      for (int r = 0; r < 4; r++){
        int rl = wr * 64 + i * 16 + q * 4 + r;
        sred[wc][rl][0] = ps[i][r];
        sred[wc][rl][1] = pd[i][r];
      }
  }
  __syncthreads();
  if (tid < 128){
    int row = rowBase + tid;
    if (row < NN){
      ssrc[row * HH + head] = sred[0][tid][0] + sred[1][tid][0];
      sdst[row * HH + head] = sred[0][tid][1] + sred[1][tid][1];
    }
  }
}

// ---------------- bucketed CSR build -----------------------------------------
__global__ __launch_bounds__(256) void bucket_scatter(const int* __restrict__ e0,
    const int* __restrict__ e1, const int* __restrict__ e2,
    int* __restrict__ gcur, unsigned* __restrict__ pairs){
  int v = blockIdx.y;
  const int* ei = (v == 0) ? e0 : ((v == 1) ? e1 : e2);
  __shared__ int cnt[NB];
  __shared__ int base[NB];
  int tid = threadIdx.x;
  for (int i = tid; i < NB; i += 256) cnt[i] = 0;
  __syncthreads();
  int estart = blockIdx.x * EPB;
  int eend = min(estart + EPB, EE);
  for (int e = estart + tid; e < eend; e += 256)
    atomicAdd(&cnt[ei[EE + e] >> 8], 1);
  __syncthreads();
  for (int i = tid; i < NB; i += 256){
    int c = cnt[i];
    base[i] = (c > 0) ? atomicAdd(&gcur[v * NB + i], c) : 0;
    cnt[i] = 0;
  }
  __syncthreads();
  for (int e = estart + tid; e < eend; e += 256){
    int s = ei[e], d = ei[EE + e];
    int b = d >> 8;
    int off = base[b] + atomicAdd(&cnt[b], 1);
    if (off < CAP)
      pairs[(size_t)(v * NB + b) * CAP + off] = ((unsigned)(d & 255) << 16) | (unsigned)s;
  }
}

__global__ __launch_bounds__(256) void bucket_scan(const int* __restrict__ gcur,
                                                   int* __restrict__ bbase){
  int v = blockIdx.x;
  __shared__ int wsum[4];
  int tid = threadIdx.x, lane = tid & 63, wv = tid >> 6;
  int val = 0;
  if (tid < NB) val = min(gcur[v * NB + tid], CAP) + min(SPB, NN - tid * SPB);
  int x = val;
#pragma unroll
  for (int off = 1; off < 64; off <<= 1){
    int t = __shfl_up(x, off);
    if (lane >= off) x += t;
  }
  if (lane == 63) wsum[wv] = x;
  __syncthreads();
  int pre = 0;
#pragma unroll
  for (int w = 0; w < 4; w++) if (w < wv) pre += wsum[w];
  if (tid < NB) bbase[v * NB + tid] = pre + x - val;
}

__global__ __launch_bounds__(256) void bucket_csr(const int* __restrict__ gcur,
    const int* __restrict__ bbase, const unsigned* __restrict__ pairs,
    int* __restrict__ rowptr_all, int* __restrict__ colx_all){
  int v = blockIdx.y, b = blockIdx.x;
  int* rowptr = rowptr_all + v * (NN + 1);
  int* colx = colx_all + (size_t)v * (EE + NN);
  __shared__ int hist[SPB];
  __shared__ int wsum[4];
  __shared__ int lcol[CAP + SPB];
  int tid = threadIdx.x, lane = tid & 63, wv = tid >> 6;
  int node0 = b << 8;
  int nvalid = min(SPB, NN - node0);
  int cnt = min(gcur[v * NB + b], CAP);
  int base = bbase[v * NB + b];
  const unsigned* pp = pairs + (size_t)(v * NB + b) * CAP;
  hist[tid] = (tid < nvalid) ? 1 : 0;   // self loop
  __syncthreads();
  for (int i = tid; i < cnt; i += 256)
    atomicAdd(&hist[pp[i] >> 16], 1);
  __syncthreads();
  int val = hist[tid];
  int x = val;
#pragma unroll
  for (int off = 1; off < 64; off <<= 1){
    int t = __shfl_up(x, off);
    if (lane >= off) x += t;
  }
  if (lane == 63) wsum[wv] = x;
  __syncthreads();
  int pre = 0;
#pragma unroll
  for (int w = 0; w < 4; w++) if (w < wv) pre += wsum[w];
  int excl = pre + x - val;
  __syncthreads();
  hist[tid] = excl + ((tid < nvalid) ? 1 : 0);   // cursor past self loop
  if (tid < nvalid){
    rowptr[node0 + tid] = base + excl;
    lcol[excl] = node0 + tid;                     // self loop first
  }
  __syncthreads();
  for (int i = tid; i < cnt; i += 256){
    unsigned p = pp[i];
    int pos = atomicAdd(&hist[p >> 16], 1);
    lcol[pos] = (int)(p & 0xffffu);
  }
  __syncthreads();
  int total = cnt + nvalid;
  for (int i = tid; i < total; i += 256) colx[base + i] = lcol[i];
  if (b == NB - 1 && tid == 0) rowptr[NN] = base + total;
}

// ---------------- per-dst softmax + aggregate (R6 structure, verbatim) -------
// One wave per (node, view); 8-deep uint2 prefetch; VGPR 48 / 8 waves/SIMD.
__global__ __launch_bounds__(256) void aggregate(const unsigned char* __restrict__ hb_all,
    const float* __restrict__ ssrc_all, const float* __restrict__ sdst_all,
    const int* __restrict__ rowptr_all, const int* __restrict__ colx_all,
    const float* __restrict__ bb, unsigned short* __restrict__ vout_all){
  int v = blockIdx.y;
  const unsigned char* hb = hb_all + (size_t)v * NN * HC;
  const float* ssrc = ssrc_all + (size_t)v * NN * HH;
  const float* sdst = sdst_all + (size_t)v * NN * HH;
  const int* rowptr = rowptr_all + v * (NN + 1);
  const int* colx = colx_all + (size_t)v * (EE + NN);

  int wave = threadIdx.x >> 6, lane = threadIdx.x & 63;
  int node = blockIdx.x * 4 + wave;
  int start = rowptr[node];
  int deg = rowptr[node + 1] - start;
  int myh = lane >> 4;
  float sdh = sdst[node * HH + myh];
  float acc[8] = {0.f, 0.f, 0.f, 0.f, 0.f, 0.f, 0.f, 0.f};
  float dsum = 0.f;

#define AGG_FMA(CH, CE) { \
    f32x2 p0 = __builtin_amdgcn_cvt_pk_f32_fp8(CH.x, false); \
    f32x2 p1 = __builtin_amdgcn_cvt_pk_f32_fp8(CH.x, true); \
    f32x2 p2 = __builtin_amdgcn_cvt_pk_f32_fp8(CH.y, false); \
    f32x2 p3 = __builtin_amdgcn_cvt_pk_f32_fp8(CH.y, true); \
    acc[0] = fmaf(CE, p0[0], acc[0]); \
    acc[1] = fmaf(CE, p0[1], acc[1]); \
    acc[2] = fmaf(CE, p1[0], acc[2]); \
    acc[3] = fmaf(CE, p1[1], acc[3]); \
    acc[4] = fmaf(CE, p2[0], acc[4]); \
    acc[5] = fmaf(CE, p2[1], acc[5]); \
    acc[6] = fmaf(CE, p3[0], acc[6]); \
    acc[7] = fmaf(CE, p3[1], acc[7]); }

  if (deg <= 64){
    int cpre = (lane < deg) ? colx[start + lane] : 0;
    uint2 h0, h1, h2, h3, h4, h5, h6, h7;
    float s0, s1, s2, s3, s4, s5, s6, s7;
#define AGG_PRO(HP, SP, P) { \
    int sp = __shfl(cpre, min(P, deg - 1)); \
    HP = *(const uint2*)&hb[(size_t)(unsigned)(sp * HC) + lane * 8]; \
    SP = ssrc[sp * HH + myh]; }
    AGG_PRO(h0, s0, 0) AGG_PRO(h1, s1, 1) AGG_PRO(h2, s2, 2) AGG_PRO(h3, s3, 3)
    AGG_PRO(h4, s4, 4) AGG_PRO(h5, s5, 5) AGG_PRO(h6, s6, 6) AGG_PRO(h7, s7, 7)
#undef AGG_PRO
#define AGG_STEP(HP, SP, P) { \
    float ce = __expf(lrelu(SP + sdh)); \
    dsum += ce; \
    uint2 ch = HP; \
    int ni = i + 8 + P; \
    if (ni < deg){ \
      int ns = __shfl(cpre, ni); \
      HP = *(const uint2*)&hb[(size_t)(unsigned)(ns * HC) + lane * 8]; \
      SP = ssrc[ns * HH + myh]; \
    } \
    AGG_FMA(ch, ce) }
    int i = 0;
    for (; i + 8 <= deg; i += 8){
      AGG_STEP(h0, s0, 0) AGG_STEP(h1, s1, 1) AGG_STEP(h2, s2, 2) AGG_STEP(h3, s3, 3)
      AGG_STEP(h4, s4, 4) AGG_STEP(h5, s5, 5) AGG_STEP(h6, s6, 6) AGG_STEP(h7, s7, 7)
    }
#undef AGG_STEP
    int rem = deg - i;
#define AGG_TAIL(HP, SP, P) if (rem > P){ \
    float ce = __expf(lrelu(SP + sdh)); \
    dsum += ce; \
    AGG_FMA(HP, ce) }
    AGG_TAIL(h0, s0, 0) AGG_TAIL(h1, s1, 1) AGG_TAIL(h2, s2, 2) AGG_TAIL(h3, s3, 3)
    AGG_TAIL(h4, s4, 4) AGG_TAIL(h5, s5, 5) AGG_TAIL(h6, s6, 6)
#undef AGG_TAIL
  } else {
    for (int i = 0; i < deg; i++){
      int src = colx[start + i];
      float sv = ssrc[src * HH + myh];
      float ce = __expf(lrelu(sv + sdh));
      dsum += ce;
      uint2 ch = *(const uint2*)&hb[(size_t)(unsigned)(src * HC) + lane * 8];
      AGG_FMA(ch, ce)
    }
  }
#undef AGG_FMA
  float rinv = 0.25f / fmaxf(dsum, 1e-16f);
#pragma unroll
  for (int j = 0; j < 8; j++) acc[j] *= rinv;
#pragma unroll
  for (int off = 16; off < 64; off <<= 1){
#pragma unroll
    for (int j = 0; j < 8; j++) acc[j] += __shfl_xor(acc[j], off);
  }
  if (lane < 16){
    const float* bv = bb + v * CC;
    unsigned short* voutv = vout_all + (size_t)v * NN * CC;
    int c0 = lane * 8;
    short8 o;
#pragma unroll
    for (int j = 0; j < 8; j++){
      float vv = acc[j] + bv[c0 + j];
      float e = vv > 0.f ? vv : (__expf(vv) - 1.f);
      o[j] = (short)f2bf(e);
    }
    *(short8*)&voutv[(size_t)node * CC + c0] = o;
  }
}

// ---------------- view fusion + classifier (persistent blocks) ---------------
__global__ __launch_bounds__(256) void fuse_classify(const unsigned short* __restrict__ vb,
    const float* __restrict__ fw, const float* __restrict__ fb,
    const float* __restrict__ w1, const float* __restrict__ b1,
    const float* __restrict__ w2, const float* __restrict__ b2,
    float* __restrict__ out){
  __shared__ float sw1[CC * 64];
  __shared__ float sfused[4][CC];
  int tid = threadIdx.x;
  for (int i = tid * 4; i < CC * 64; i += 1024)
    *(float4*)&sw1[i] = *(const float4*)&w1[i];
  __syncthreads();
  int wave = tid >> 6, lane = tid & 63;
  float fwa = fw[lane * 2], fwb = fw[lane * 2 + 1];
  float w2a = w2[lane * 2], w2b = w2[lane * 2 + 1];
  float b1l = b1[lane];
  for (int g = 0; g < 8; g++){
    int node = blockIdx.x * 32 + g * 4 + wave;
    if (node < NN){
      unsigned r0 = *(const unsigned*)&vb[(size_t)(0 * NN + node) * CC + lane * 2];
      unsigned r1 = *(const unsigned*)&vb[(size_t)(1 * NN + node) * CC + lane * 2];
      unsigned r2 = *(const unsigned*)&vb[(size_t)(2 * NN + node) * CC + lane * 2];
      float v0x = bf2f((short)(r0 & 0xffffu)), v0y = bf2f((short)(r0 >> 16));
      float v1x = bf2f((short)(r1 & 0xffffu)), v1y = bf2f((short)(r1 >> 16));
      float v2x = bf2f((short)(r2 & 0xffffu)), v2y = bf2f((short)(r2 >> 16));
      float s0 = wave_sum64(v0x * fwa + v0y * fwb) + fb[0];
      float s1 = wave_sum64(v1x * fwa + v1y * fwb) + fb[0];
      float s2 = wave_sum64(v2x * fwa + v2y * fwb) + fb[0];
      float mx = fmaxf(s0, fmaxf(s1, s2));
      float e0 = __expf(s0 - mx), e1 = __expf(s1 - mx), e2 = __expf(s2 - mx);
      float rs = 1.f / (e0 + e1 + e2);
      float w0 = e0 * rs, w1v = e1 * rs, w2v = e2 * rs;
      float f0 = w0 * v0x + w1v * v1x + w2v * v2x;
      float f1 = w0 * v0y + w1v * v1y + w2v * v2y;
      sfused[wave][lane * 2]     = f0;
      sfused[wave][lane * 2 + 1] = f1;
      if (lane < 3){
        float wv = (lane == 0) ? w0 : ((lane == 1) ? w1v : w2v);
        out[2 * NN + node * 3 + lane] = wv;
      }
      __builtin_amdgcn_s_waitcnt(0);   // drain wave-local LDS writes
      float hc = b1l;
#pragma unroll 8
      for (int c = 0; c < CC; c++)
        hc = fmaf(sfused[wave][c], sw1[c * 64 + lane], hc);
      hc = fmaxf(hc, 0.f);
      float l0 = wave_sum64(hc * w2a);
      float l1 = wave_sum64(hc * w2b);
      if (lane == 0){
        out[node * 2]     = l0 + b2[0];
        out[node * 2 + 1] = l1 + b2[1];
      }
    }
  }
}

// ---------------- launch -----------------------------------------------------
extern "C" void kernel_launch(void* const* d_in, const int* in_sizes, int n_in,
                              void* d_out, int out_size, void* d_ws, size_t ws_size,
                              hipStream_t stream){
  const float* x      = (const float*)d_in[0];
  const int*   e0     = (const int*)d_in[1];
  const int*   e1     = (const int*)d_in[2];
  const int*   e2     = (const int*)d_in[3];
  const float* W      = (const float*)d_in[4];
  const float* a_src  = (const float*)d_in[5];
  const float* a_dst  = (const float*)d_in[6];
  const float* bb     = (const float*)d_in[7];
  const float* fus_w  = (const float*)d_in[8];
  const float* fus_b  = (const float*)d_in[9];
  const float* cls_w1 = (const float*)d_in[10];
  const float* cls_b1 = (const float*)d_in[11];
  const float* cls_w2 = (const float*)d_in[12];
  const float* cls_b2 = (const float*)d_in[13];
  float* out = (float*)d_out;

  // workspace layout (~157 MB). pairs (early) and vout (late) alias.
  unsigned short* xb = (unsigned short*)d_ws;                   // NN*FIN bf16
  unsigned char* hb  = (unsigned char*)(xb + (size_t)NN * FIN); // VV*NN*HC fp8
  unsigned short* wp = (unsigned short*)(hb + (size_t)VV * NN * HC); // VV*FIN*HC bf16
  float* ssrc = (float*)(wp + (size_t)VV * FIN * HC);           // VV*NN*HH
  float* sdst = ssrc + (size_t)VV * NN * HH;                    // VV*NN*HH
  int* gcur   = (int*)(sdst + (size_t)VV * NN * HH);            // VV*NB
  int* bbase  = gcur + VV * NB;                                 // VV*NB
  int* rowptr = bbase + VV * NB;                                // VV*(NN+1)
  int* colx   = rowptr + VV * (NN + 1);                         // VV*(EE+NN)
  unsigned* pairs = (unsigned*)(colx + (size_t)VV * (EE + NN)); // VV*NB*CAP (early)
  unsigned short* voutb = (unsigned short*)pairs;               // VV*NN*CC bf16 (late)

  hipMemsetAsync(gcur, 0, (size_t)VV * NB * sizeof(int), stream);
  cast_x<<<12500, 256, 0, stream>>>(x, xb);
  prep_w_all<<<1536, 256, 0, stream>>>(W, wp);
  dim3 p1grid((EE + EPB - 1) / EPB, 3);   // 391 x 3
  bucket_scatter<<<p1grid, 256, 0, stream>>>(e0, e1, e2, gcur, pairs);
  bucket_scan<<<3, 256, 0, stream>>>(gcur, bbase);
  dim3 p2grid(NB, 3);
  bucket_csr<<<p2grid, 256, 0, stream>>>(gcur, bbase, pairs, rowptr, colx);

  dim3 ggrid(391, 4, 3);
  gemm_mfma_scores<<<ggrid, 256, 0, stream>>>(xb, wp, hb, a_src, a_dst, ssrc, sdst);
  dim3 agrid(12500, 3);
  aggregate<<<agrid, 256, 0, stream>>>(hb, ssrc, sdst, rowptr, colx, bb, voutb);
  fuse_classify<<<1563, 256, 0, stream>>>(voutb, fus_w, fus_b, cls_w1, cls_b1,
                                          cls_w2, cls_b2, out);
}

// Round 10
// 546.346 us; speedup vs baseline: 1.2405x; 1.0661x over previous
//
#include <hip/hip_runtime.h>
#include <math.h>

#define NN 50000
#define EE 800000
#define FIN 256
#define HH 4
#define CC 128
#define HC 512   // HH*CC
#define VV 3

// bucketed CSR build
#define NB 196    // buckets: dst >> 8
#define SPB 256   // nodes per bucket
#define CAP 4608  // max edges per bucket (mean 4096, +8 sigma)
#define EPB 2048  // edges per phase-1 block (small => high occupancy)

typedef __attribute__((ext_vector_type(8))) short short8;
typedef __attribute__((ext_vector_type(4))) float f32x4;
typedef __attribute__((ext_vector_type(2))) float f32x2;

__device__ __forceinline__ float lrelu(float x){ return x > 0.f ? x : 0.2f*x; }

__device__ __forceinline__ unsigned short f2bf(float f){
  unsigned u = __float_as_uint(f);
  u += 0x7fffu + ((u >> 16) & 1);   // round-to-nearest-even
  return (unsigned short)(u >> 16);
}
__device__ __forceinline__ float bf2f(short b){
  return __uint_as_float(((unsigned)b & 0xffffu) << 16);
}

__device__ __forceinline__ float wave_sum64(float v){
#pragma unroll
  for (int off = 32; off; off >>= 1) v += __shfl_xor(v, off);
  return v;
}

// ---------------- casts ------------------------------------------------------
__global__ __launch_bounds__(256) void cast_x(const float* __restrict__ x,
                                              unsigned short* __restrict__ xb){
  int t = blockIdx.x * 256 + threadIdx.x;      // one thread per 4 elements
  float4 v = *(const float4*)&x[(size_t)t * 4];
  ushort4 o;
  o.x = f2bf(v.x); o.y = f2bf(v.y); o.z = f2bf(v.z); o.w = f2bf(v.w);
  *(ushort4*)&xb[(size_t)t * 4] = o;
}

// W is [VV][FIN][HC] fp32 -> wp[v] layout [FIN/32][HC][32] bf16
__global__ __launch_bounds__(256) void prep_w_all(const float* __restrict__ W,
                                                  unsigned short* __restrict__ wp){
  int t = blockIdx.x * 256 + threadIdx.x;      // VV*131072 threads
  int v = t >> 17;                              // FIN*HC = 131072 = 2^17
  int tl = t & 131071;
  int k = tl >> 9, n = tl & 511;
  wp[(size_t)v * (FIN * HC) + (size_t)(k >> 5) * (HC * 32) + n * 32 + (k & 31)] = f2bf(W[t]);
}

// ---------------- MFMA GEMM + fused attention scores -------------------------
// grid (391, 3 views). Head loop INSIDE the block: A fragments for all 8 kt
// loaded ONCE into registers (af[8][4], ~128 VGPR) and reused across 4 heads;
// B double-buffered from L2-hot wp. launch_bounds(256,2) -> 2 waves/SIMD,
// cross-wave overlap hides B latency. h stored fp8 e4m3.
__global__ __launch_bounds__(256, 2) void gemm_mfma_scores(
    const unsigned short* __restrict__ xb, const unsigned short* __restrict__ wp_all,
    unsigned char* __restrict__ hb_all,
    const float* __restrict__ a_src, const float* __restrict__ a_dst,
    float* __restrict__ ssrc_all, float* __restrict__ sdst_all){
  __shared__ float sred[2][128][2];
  int tid = threadIdx.x;
  int wave = tid >> 6, lane = tid & 63;
  int l16 = lane & 15, q = lane >> 4;
  int wr = wave >> 1, wc = wave & 1;
  int v = blockIdx.y;
  int rowBase = blockIdx.x * 128;

  const unsigned short* wp = wp_all + (size_t)v * FIN * HC;
  unsigned char* hb = hb_all + (size_t)v * NN * HC;
  float* ssrc = ssrc_all + (size_t)v * NN * HH;
  float* sdst = sdst_all + (size_t)v * NN * HH;

  // A fragments: all 8 kt, once per block
  short8 af[8][4];
#pragma unroll
  for (int i = 0; i < 4; i++){
    int row = min(rowBase + wr * 64 + i * 16 + l16, NN - 1);
    const unsigned short* aprow = xb + (size_t)row * FIN + q * 8;
#pragma unroll
    for (int kt = 0; kt < 8; kt++)
      af[kt][i] = *(const short8*)(aprow + kt * 32);
  }

  for (int head = 0; head < HH; head++){
    int colBase = head * 128;
    const unsigned short* bp[4];
#pragma unroll
    for (int j = 0; j < 4; j++)
      bp[j] = wp + (size_t)(colBase + wc * 64 + j * 16 + l16) * 32 + q * 8;
    f32x4 acc[4][4] = {};
    short8 bf[2][4];
#pragma unroll
    for (int j = 0; j < 4; j++) bf[0][j] = *(const short8*)(bp[j]);
#pragma unroll
    for (int kt = 0; kt < 8; kt++){
      int cur = kt & 1, nxt = cur ^ 1;
      if (kt < 7){
#pragma unroll
        for (int j = 0; j < 4; j++)
          bf[nxt][j] = *(const short8*)(bp[j] + (size_t)(kt + 1) * (HC * 32));
      }
#pragma unroll
      for (int i = 0; i < 4; i++)
#pragma unroll
        for (int j = 0; j < 4; j++)
          acc[i][j] = __builtin_amdgcn_mfma_f32_16x16x32_bf16(af[kt][i], bf[cur][j], acc[i][j], 0, 0, 0);
    }
    // epilogue 1: store hb as fp8. D layout: row=(lane>>4)*4+reg, col=lane&15
#pragma unroll
    for (int i = 0; i < 4; i++){
#pragma unroll
      for (int r = 0; r < 4; r++){
        int row = rowBase + wr * 64 + i * 16 + q * 4 + r;
        if (row < NN){
          int p01 = __builtin_amdgcn_cvt_pk_fp8_f32(acc[i][0][r], acc[i][1][r], 0, false);
          int p23 = __builtin_amdgcn_cvt_pk_fp8_f32(acc[i][2][r], acc[i][3][r], 0, false);
          size_t rb = (size_t)row * HC + colBase + wc * 64 + l16;
          hb[rb +  0] = (unsigned char)(p01 & 0xff);
          hb[rb + 16] = (unsigned char)((p01 >> 8) & 0xff);
          hb[rb + 32] = (unsigned char)(p23 & 0xff);
          hb[rb + 48] = (unsigned char)((p23 >> 8) & 0xff);
        }
      }
    }
    // epilogue 2: fused scores for this head
    float asv[4], adv[4];
#pragma unroll
    for (int j = 0; j < 4; j++){
      int c = wc * 64 + j * 16 + l16;
      asv[j] = a_src[(v * HH + head) * CC + c];
      adv[j] = a_dst[(v * HH + head) * CC + c];
    }
    float ps[4][4], pd[4][4];
#pragma unroll
    for (int i = 0; i < 4; i++)
#pragma unroll
      for (int r = 0; r < 4; r++){
        float s = 0.f, d = 0.f;
#pragma unroll
        for (int j = 0; j < 4; j++){
          s = fmaf(acc[i][j][r], asv[j], s);
          d = fmaf(acc[i][j][r], adv[j], d);
        }
        ps[i][r] = s; pd[i][r] = d;
      }
#pragma unroll
    for (int off = 1; off < 16; off <<= 1)
#pragma unroll
      for (int i = 0; i < 4; i++)
#pragma unroll
        for (int r = 0; r < 4; r++){
          ps[i][r] += __shfl_xor(ps[i][r], off);
          pd[i][r] += __shfl_xor(pd[i][r], off);
        }
    __syncthreads();   // sred write-after-read across head iterations
    if (l16 == 0){
#pragma unroll
      for (int i = 0; i < 4; i++)
#pragma unroll
        for (int r = 0; r < 4; r++){
          int rl = wr * 64 + i * 16 + q * 4 + r;
          sred[wc][rl][0] = ps[i][r];
          sred[wc][rl][1] = pd[i][r];
        }
    }
    __syncthreads();
    if (tid < 128){
      int row = rowBase + tid;
      if (row < NN){
        ssrc[row * HH + head] = sred[0][tid][0] + sred[1][tid][0];
        sdst[row * HH + head] = sred[0][tid][1] + sred[1][tid][1];
      }
    }
  }
}

// ---------------- bucketed CSR build -----------------------------------------
__global__ __launch_bounds__(256) void bucket_scatter(const int* __restrict__ e0,
    const int* __restrict__ e1, const int* __restrict__ e2,
    int* __restrict__ gcur, unsigned* __restrict__ pairs){
  int v = blockIdx.y;
  const int* ei = (v == 0) ? e0 : ((v == 1) ? e1 : e2);
  __shared__ int cnt[NB];
  __shared__ int base[NB];
  int tid = threadIdx.x;
  for (int i = tid; i < NB; i += 256) cnt[i] = 0;
  __syncthreads();
  int estart = blockIdx.x * EPB;
  int eend = min(estart + EPB, EE);
  for (int e = estart + tid; e < eend; e += 256)
    atomicAdd(&cnt[ei[EE + e] >> 8], 1);
  __syncthreads();
  for (int i = tid; i < NB; i += 256){
    int c = cnt[i];
    base[i] = (c > 0) ? atomicAdd(&gcur[v * NB + i], c) : 0;
    cnt[i] = 0;
  }
  __syncthreads();
  for (int e = estart + tid; e < eend; e += 256){
    int s = ei[e], d = ei[EE + e];
    int b = d >> 8;
    int off = base[b] + atomicAdd(&cnt[b], 1);
    if (off < CAP)
      pairs[(size_t)(v * NB + b) * CAP + off] = ((unsigned)(d & 255) << 16) | (unsigned)s;
  }
}

__global__ __launch_bounds__(256) void bucket_scan(const int* __restrict__ gcur,
                                                   int* __restrict__ bbase){
  int v = blockIdx.x;
  __shared__ int wsum[4];
  int tid = threadIdx.x, lane = tid & 63, wv = tid >> 6;
  int val = 0;
  if (tid < NB) val = min(gcur[v * NB + tid], CAP) + min(SPB, NN - tid * SPB);
  int x = val;
#pragma unroll
  for (int off = 1; off < 64; off <<= 1){
    int t = __shfl_up(x, off);
    if (lane >= off) x += t;
  }
  if (lane == 63) wsum[wv] = x;
  __syncthreads();
  int pre = 0;
#pragma unroll
  for (int w = 0; w < 4; w++) if (w < wv) pre += wsum[w];
  if (tid < NB) bbase[v * NB + tid] = pre + x - val;
}

__global__ __launch_bounds__(256) void bucket_csr(const int* __restrict__ gcur,
    const int* __restrict__ bbase, const unsigned* __restrict__ pairs,
    int* __restrict__ rowptr_all, int* __restrict__ colx_all){
  int v = blockIdx.y, b = blockIdx.x;
  int* rowptr = rowptr_all + v * (NN + 1);
  int* colx = colx_all + (size_t)v * (EE + NN);
  __shared__ int hist[SPB];
  __shared__ int wsum[4];
  __shared__ int lcol[CAP + SPB];
  int tid = threadIdx.x, lane = tid & 63, wv = tid >> 6;
  int node0 = b << 8;
  int nvalid = min(SPB, NN - node0);
  int cnt = min(gcur[v * NB + b], CAP);
  int base = bbase[v * NB + b];
  const unsigned* pp = pairs + (size_t)(v * NB + b) * CAP;
  hist[tid] = (tid < nvalid) ? 1 : 0;   // self loop
  __syncthreads();
  for (int i = tid; i < cnt; i += 256)
    atomicAdd(&hist[pp[i] >> 16], 1);
  __syncthreads();
  int val = hist[tid];
  int x = val;
#pragma unroll
  for (int off = 1; off < 64; off <<= 1){
    int t = __shfl_up(x, off);
    if (lane >= off) x += t;
  }
  if (lane == 63) wsum[wv] = x;
  __syncthreads();
  int pre = 0;
#pragma unroll
  for (int w = 0; w < 4; w++) if (w < wv) pre += wsum[w];
  int excl = pre + x - val;
  __syncthreads();
  hist[tid] = excl + ((tid < nvalid) ? 1 : 0);   // cursor past self loop
  if (tid < nvalid){
    rowptr[node0 + tid] = base + excl;
    lcol[excl] = node0 + tid;                     // self loop first
  }
  __syncthreads();
  for (int i = tid; i < cnt; i += 256){
    unsigned p = pp[i];
    int pos = atomicAdd(&hist[p >> 16], 1);
    lcol[pos] = (int)(p & 0xffffu);
  }
  __syncthreads();
  int total = cnt + nvalid;
  for (int i = tid; i < total; i += 256) colx[base + i] = lcol[i];
  if (b == NB - 1 && tid == 0) rowptr[NN] = base + total;
}

// ---------------- per-dst softmax + aggregate (R6 structure, verbatim) -------
__global__ __launch_bounds__(256) void aggregate(const unsigned char* __restrict__ hb_all,
    const float* __restrict__ ssrc_all, const float* __restrict__ sdst_all,
    const int* __restrict__ rowptr_all, const int* __restrict__ colx_all,
    const float* __restrict__ bb, unsigned short* __restrict__ vout_all){
  int v = blockIdx.y;
  const unsigned char* hb = hb_all + (size_t)v * NN * HC;
  const float* ssrc = ssrc_all + (size_t)v * NN * HH;
  const float* sdst = sdst_all + (size_t)v * NN * HH;
  const int* rowptr = rowptr_all + v * (NN + 1);
  const int* colx = colx_all + (size_t)v * (EE + NN);

  int wave = threadIdx.x >> 6, lane = threadIdx.x & 63;
  int node = blockIdx.x * 4 + wave;
  int start = rowptr[node];
  int deg = rowptr[node + 1] - start;
  int myh = lane >> 4;
  float sdh = sdst[node * HH + myh];
  float acc[8] = {0.f, 0.f, 0.f, 0.f, 0.f, 0.f, 0.f, 0.f};
  float dsum = 0.f;

#define AGG_FMA(CH, CE) { \
    f32x2 p0 = __builtin_amdgcn_cvt_pk_f32_fp8(CH.x, false); \
    f32x2 p1 = __builtin_amdgcn_cvt_pk_f32_fp8(CH.x, true); \
    f32x2 p2 = __builtin_amdgcn_cvt_pk_f32_fp8(CH.y, false); \
    f32x2 p3 = __builtin_amdgcn_cvt_pk_f32_fp8(CH.y, true); \
    acc[0] = fmaf(CE, p0[0], acc[0]); \
    acc[1] = fmaf(CE, p0[1], acc[1]); \
    acc[2] = fmaf(CE, p1[0], acc[2]); \
    acc[3] = fmaf(CE, p1[1], acc[3]); \
    acc[4] = fmaf(CE, p2[0], acc[4]); \
    acc[5] = fmaf(CE, p2[1], acc[5]); \
    acc[6] = fmaf(CE, p3[0], acc[6]); \
    acc[7] = fmaf(CE, p3[1], acc[7]); }

  if (deg <= 64){
    int cpre = (lane < deg) ? colx[start + lane] : 0;
    uint2 h0, h1, h2, h3, h4, h5, h6, h7;
    float s0, s1, s2, s3, s4, s5, s6, s7;
#define AGG_PRO(HP, SP, P) { \
    int sp = __shfl(cpre, min(P, deg - 1)); \
    HP = *(const uint2*)&hb[(size_t)(unsigned)(sp * HC) + lane * 8]; \
    SP = ssrc[sp * HH + myh]; }
    AGG_PRO(h0, s0, 0) AGG_PRO(h1, s1, 1) AGG_PRO(h2, s2, 2) AGG_PRO(h3, s3, 3)
    AGG_PRO(h4, s4, 4) AGG_PRO(h5, s5, 5) AGG_PRO(h6, s6, 6) AGG_PRO(h7, s7, 7)
#undef AGG_PRO
#define AGG_STEP(HP, SP, P) { \
    float ce = __expf(lrelu(SP + sdh)); \
    dsum += ce; \
    uint2 ch = HP; \
    int ni = i + 8 + P; \
    if (ni < deg){ \
      int ns = __shfl(cpre, ni); \
      HP = *(const uint2*)&hb[(size_t)(unsigned)(ns * HC) + lane * 8]; \
      SP = ssrc[ns * HH + myh]; \
    } \
    AGG_FMA(ch, ce) }
    int i = 0;
    for (; i + 8 <= deg; i += 8){
      AGG_STEP(h0, s0, 0) AGG_STEP(h1, s1, 1) AGG_STEP(h2, s2, 2) AGG_STEP(h3, s3, 3)
      AGG_STEP(h4, s4, 4) AGG_STEP(h5, s5, 5) AGG_STEP(h6, s6, 6) AGG_STEP(h7, s7, 7)
    }
#undef AGG_STEP
    int rem = deg - i;
#define AGG_TAIL(HP, SP, P) if (rem > P){ \
    float ce = __expf(lrelu(SP + sdh)); \
    dsum += ce; \
    AGG_FMA(HP, ce) }
    AGG_TAIL(h0, s0, 0) AGG_TAIL(h1, s1, 1) AGG_TAIL(h2, s2, 2) AGG_TAIL(h3, s3, 3)
    AGG_TAIL(h4, s4, 4) AGG_TAIL(h5, s5, 5) AGG_TAIL(h6, s6, 6)
#undef AGG_TAIL
  } else {
    for (int i = 0; i < deg; i++){
      int src = colx[start + i];
      float sv = ssrc[src * HH + myh];
      float ce = __expf(lrelu(sv + sdh));
      dsum += ce;
      uint2 ch = *(const uint2*)&hb[(size_t)(unsigned)(src * HC) + lane * 8];
      AGG_FMA(ch, ce)
    }
  }
#undef AGG_FMA
  float rinv = 0.25f / fmaxf(dsum, 1e-16f);
#pragma unroll
  for (int j = 0; j < 8; j++) acc[j] *= rinv;
#pragma unroll
  for (int off = 16; off < 64; off <<= 1){
#pragma unroll
    for (int j = 0; j < 8; j++) acc[j] += __shfl_xor(acc[j], off);
  }
  if (lane < 16){
    const float* bv = bb + v * CC;
    unsigned short* voutv = vout_all + (size_t)v * NN * CC;
    int c0 = lane * 8;
    short8 o;
#pragma unroll
    for (int j = 0; j < 8; j++){
      float vv = acc[j] + bv[c0 + j];
      float e = vv > 0.f ? vv : (__expf(vv) - 1.f);
      o[j] = (short)f2bf(e);
    }
    *(short8*)&voutv[(size_t)node * CC + c0] = o;
  }
}

// ---------------- view fusion + classifier (persistent blocks) ---------------
__global__ __launch_bounds__(256) void fuse_classify(const unsigned short* __restrict__ vb,
    const float* __restrict__ fw, const float* __restrict__ fb,
    const float* __restrict__ w1, const float* __restrict__ b1,
    const float* __restrict__ w2, const float* __restrict__ b2,
    float* __restrict__ out){
  __shared__ float sw1[CC * 64];
  __shared__ float sfused[4][CC];
  int tid = threadIdx.x;
  for (int i = tid * 4; i < CC * 64; i += 1024)
    *(float4*)&sw1[i] = *(const float4*)&w1[i];
  __syncthreads();
  int wave = tid >> 6, lane = tid & 63;
  float fwa = fw[lane * 2], fwb = fw[lane * 2 + 1];
  float w2a = w2[lane * 2], w2b = w2[lane * 2 + 1];
  float b1l = b1[lane];
  for (int g = 0; g < 8; g++){
    int node = blockIdx.x * 32 + g * 4 + wave;
    if (node < NN){
      unsigned r0 = *(const unsigned*)&vb[(size_t)(0 * NN + node) * CC + lane * 2];
      unsigned r1 = *(const unsigned*)&vb[(size_t)(1 * NN + node) * CC + lane * 2];
      unsigned r2 = *(const unsigned*)&vb[(size_t)(2 * NN + node) * CC + lane * 2];
      float v0x = bf2f((short)(r0 & 0xffffu)), v0y = bf2f((short)(r0 >> 16));
      float v1x = bf2f((short)(r1 & 0xffffu)), v1y = bf2f((short)(r1 >> 16));
      float v2x = bf2f((short)(r2 & 0xffffu)), v2y = bf2f((short)(r2 >> 16));
      float s0 = wave_sum64(v0x * fwa + v0y * fwb) + fb[0];
      float s1 = wave_sum64(v1x * fwa + v1y * fwb) + fb[0];
      float s2 = wave_sum64(v2x * fwa + v2y * fwb) + fb[0];
      float mx = fmaxf(s0, fmaxf(s1, s2));
      float e0 = __expf(s0 - mx), e1 = __expf(s1 - mx), e2 = __expf(s2 - mx);
      float rs = 1.f / (e0 + e1 + e2);
      float w0 = e0 * rs, w1v = e1 * rs, w2v = e2 * rs;
      float f0 = w0 * v0x + w1v * v1x + w2v * v2x;
      float f1 = w0 * v0y + w1v * v1y + w2v * v2y;
      sfused[wave][lane * 2]     = f0;
      sfused[wave][lane * 2 + 1] = f1;
      if (lane < 3){
        float wv = (lane == 0) ? w0 : ((lane == 1) ? w1v : w2v);
        out[2 * NN + node * 3 + lane] = wv;
      }
      __builtin_amdgcn_s_waitcnt(0);   // drain wave-local LDS writes
      float hc = b1l;
#pragma unroll 8
      for (int c = 0; c < CC; c++)
        hc = fmaf(sfused[wave][c], sw1[c * 64 + lane], hc);
      hc = fmaxf(hc, 0.f);
      float l0 = wave_sum64(hc * w2a);
      float l1 = wave_sum64(hc * w2b);
      if (lane == 0){
        out[node * 2]     = l0 + b2[0];
        out[node * 2 + 1] = l1 + b2[1];
      }
    }
  }
}

// ---------------- launch -----------------------------------------------------
extern "C" void kernel_launch(void* const* d_in, const int* in_sizes, int n_in,
                              void* d_out, int out_size, void* d_ws, size_t ws_size,
                              hipStream_t stream){
  const float* x      = (const float*)d_in[0];
  const int*   e0     = (const int*)d_in[1];
  const int*   e1     = (const int*)d_in[2];
  const int*   e2     = (const int*)d_in[3];
  const float* W      = (const float*)d_in[4];
  const float* a_src  = (const float*)d_in[5];
  const float* a_dst  = (const float*)d_in[6];
  const float* bb     = (const float*)d_in[7];
  const float* fus_w  = (const float*)d_in[8];
  const float* fus_b  = (const float*)d_in[9];
  const float* cls_w1 = (const float*)d_in[10];
  const float* cls_b1 = (const float*)d_in[11];
  const float* cls_w2 = (const float*)d_in[12];
  const float* cls_b2 = (const float*)d_in[13];
  float* out = (float*)d_out;

  // workspace layout (~157 MB). pairs (early) and vout (late) alias.
  unsigned short* xb = (unsigned short*)d_ws;                   // NN*FIN bf16
  unsigned char* hb  = (unsigned char*)(xb + (size_t)NN * FIN); // VV*NN*HC fp8
  unsigned short* wp = (unsigned short*)(hb + (size_t)VV * NN * HC); // VV*FIN*HC bf16
  float* ssrc = (float*)(wp + (size_t)VV * FIN * HC);           // VV*NN*HH
  float* sdst = ssrc + (size_t)VV * NN * HH;                    // VV*NN*HH
  int* gcur   = (int*)(sdst + (size_t)VV * NN * HH);            // VV*NB
  int* bbase  = gcur + VV * NB;                                 // VV*NB
  int* rowptr = bbase + VV * NB;                                // VV*(NN+1)
  int* colx   = rowptr + VV * (NN + 1);                         // VV*(EE+NN)
  unsigned* pairs = (unsigned*)(colx + (size_t)VV * (EE + NN)); // VV*NB*CAP (early)
  unsigned short* voutb = (unsigned short*)pairs;               // VV*NN*CC bf16 (late)

  hipMemsetAsync(gcur, 0, (size_t)VV * NB * sizeof(int), stream);
  cast_x<<<12500, 256, 0, stream>>>(x, xb);
  prep_w_all<<<1536, 256, 0, stream>>>(W, wp);
  dim3 p1grid((EE + EPB - 1) / EPB, 3);   // 391 x 3
  bucket_scatter<<<p1grid, 256, 0, stream>>>(e0, e1, e2, gcur, pairs);
  bucket_scan<<<3, 256, 0, stream>>>(gcur, bbase);
  dim3 p2grid(NB, 3);
  bucket_csr<<<p2grid, 256, 0, stream>>>(gcur, bbase, pairs, rowptr, colx);

  dim3 ggrid(391, 3);
  gemm_mfma_scores<<<ggrid, 256, 0, stream>>>(xb, wp, hb, a_src, a_dst, ssrc, sdst);
  dim3 agrid(12500, 3);
  aggregate<<<agrid, 256, 0, stream>>>(hb, ssrc, sdst, rowptr, colx, bb, voutb);
  fuse_classify<<<1563, 256, 0, stream>>>(voutb, fus_w, fus_b, cls_w1, cls_b1,
                                          cls_w2, cls_b2, out);
}

// Round 11
// 545.085 us; speedup vs baseline: 1.2434x; 1.0023x over previous
//
#include <hip/hip_runtime.h>
#include <math.h>

#define NN 50000
#define EE 800000
#define FIN 256
#define HH 4
#define CC 128
#define HC 512   // HH*CC
#define VV 3

// bucketed CSR build
#define NB 196    // buckets: dst >> 8
#define SPB 256   // nodes per bucket
#define CAP 4608  // max edges per bucket (mean 4096, +8 sigma)
#define EPB 2048  // edges per phase-1 block (small => high occupancy)

typedef __attribute__((ext_vector_type(8))) short short8;
typedef __attribute__((ext_vector_type(4))) float f32x4;
typedef __attribute__((ext_vector_type(2))) float f32x2;

__device__ __forceinline__ float lrelu(float x){ return x > 0.f ? x : 0.2f*x; }

__device__ __forceinline__ unsigned short f2bf(float f){
  unsigned u = __float_as_uint(f);
  u += 0x7fffu + ((u >> 16) & 1);   // round-to-nearest-even
  return (unsigned short)(u >> 16);
}
__device__ __forceinline__ float bf2f(short b){
  return __uint_as_float(((unsigned)b & 0xffffu) << 16);
}

__device__ __forceinline__ float wave_sum64(float v){
#pragma unroll
  for (int off = 32; off; off >>= 1) v += __shfl_xor(v, off);
  return v;
}

__device__ __forceinline__ void async16(void* lds, const void* g){
  __builtin_amdgcn_global_load_lds(
      (const __attribute__((address_space(1))) unsigned*)g,
      (__attribute__((address_space(3))) unsigned*)lds, 16, 0, 0);
}

// ---------------- casts ------------------------------------------------------
__global__ __launch_bounds__(256) void cast_x(const float* __restrict__ x,
                                              unsigned short* __restrict__ xb){
  int t = blockIdx.x * 256 + threadIdx.x;      // one thread per 4 elements
  float4 v = *(const float4*)&x[(size_t)t * 4];
  ushort4 o;
  o.x = f2bf(v.x); o.y = f2bf(v.y); o.z = f2bf(v.z); o.w = f2bf(v.w);
  *(ushort4*)&xb[(size_t)t * 4] = o;
}

// W is [VV][FIN][HC] fp32 -> wp[v] layout [FIN/32][HC][32] bf16
__global__ __launch_bounds__(256) void prep_w_all(const float* __restrict__ W,
                                                  unsigned short* __restrict__ wp){
  int t = blockIdx.x * 256 + threadIdx.x;      // VV*131072 threads
  int v = t >> 17;                              // FIN*HC = 131072 = 2^17
  int tl = t & 131071;
  int k = tl >> 9, n = tl & 511;
  wp[(size_t)v * (FIN * HC) + (size_t)(k >> 5) * (HC * 32) + n * 32 + (k & 31)] = f2bf(W[t]);
}

// ---------------- MFMA GEMM + fused attention scores (R6 LDS version) --------
// grid (391, 4 heads, 3 views). m97-style global_load_lds 16B staging; 4692
// blocks give ~12 waves/CU of cross-wave overlap. h stored fp8 e4m3.
__global__ __launch_bounds__(256) void gemm_mfma_scores(
    const unsigned short* __restrict__ xb, const unsigned short* __restrict__ wp_all,
    unsigned char* __restrict__ hb_all,
    const float* __restrict__ a_src, const float* __restrict__ a_dst,
    float* __restrict__ ssrc_all, float* __restrict__ sdst_all){
  __shared__ short As[128 * 32];
  __shared__ short Bs[128 * 32];
  __shared__ float sred[2][128][2];
  int tid = threadIdx.x;
  int wave = tid >> 6, lane = tid & 63;
  int l16 = lane & 15, q = lane >> 4;
  int wr = wave >> 1, wc = wave & 1;
  int head = blockIdx.y, v = blockIdx.z;
  int rowBase = blockIdx.x * 128, colBase = head * 128;

  const unsigned short* wp = wp_all + (size_t)v * FIN * HC;
  unsigned char* hb = hb_all + (size_t)v * NN * HC;
  const float* a_src_v = a_src + v * HH * CC;
  const float* a_dst_v = a_dst + v * HH * CC;
  float* ssrc = ssrc_all + (size_t)v * NN * HH;
  float* sdst = sdst_all + (size_t)v * NN * HH;

  int off0 = wave * 2048 + lane * 16;   // byte offset in 8 KB tile
  int off1 = off0 + 1024;
  int arow0 = off0 >> 6, akb0 = (off0 & 63) >> 1;
  int arow1 = off1 >> 6, akb1 = (off1 & 63) >> 1;
  size_t ga0 = (size_t)min(rowBase + arow0, NN - 1) * FIN + akb0;
  size_t ga1 = (size_t)min(rowBase + arow1, NN - 1) * FIN + akb1;
  const unsigned short* wpc = wp + (size_t)colBase * 32;

  f32x4 acc[4][4] = {};
  for (int kt = 0; kt < 8; kt++){
    async16((char*)As + wave * 2048,        xb + ga0 + kt * 32);
    async16((char*)As + wave * 2048 + 1024, xb + ga1 + kt * 32);
    async16((char*)Bs + wave * 2048,        wpc + (size_t)kt * (HC * 32) + (off0 >> 1));
    async16((char*)Bs + wave * 2048 + 1024, wpc + (size_t)kt * (HC * 32) + (off1 >> 1));
    __syncthreads();
    short8 af[4], bf[4];
#pragma unroll
    for (int i = 0; i < 4; i++)
      af[i] = *(const short8*)&As[(wr * 64 + i * 16 + l16) * 32 + q * 8];
#pragma unroll
    for (int j = 0; j < 4; j++)
      bf[j] = *(const short8*)&Bs[(wc * 64 + j * 16 + l16) * 32 + q * 8];
#pragma unroll
    for (int i = 0; i < 4; i++)
#pragma unroll
      for (int j = 0; j < 4; j++)
        acc[i][j] = __builtin_amdgcn_mfma_f32_16x16x32_bf16(af[i], bf[j], acc[i][j], 0, 0, 0);
    __syncthreads();
  }
  // epilogue 1: store hb as fp8. D layout: row=(lane>>4)*4+reg, col=lane&15
#pragma unroll
  for (int i = 0; i < 4; i++){
#pragma unroll
    for (int r = 0; r < 4; r++){
      int row = rowBase + wr * 64 + i * 16 + q * 4 + r;
      if (row < NN){
        int p01 = __builtin_amdgcn_cvt_pk_fp8_f32(acc[i][0][r], acc[i][1][r], 0, false);
        int p23 = __builtin_amdgcn_cvt_pk_fp8_f32(acc[i][2][r], acc[i][3][r], 0, false);
        size_t rb = (size_t)row * HC + colBase + wc * 64 + l16;
        hb[rb +  0] = (unsigned char)(p01 & 0xff);
        hb[rb + 16] = (unsigned char)((p01 >> 8) & 0xff);
        hb[rb + 32] = (unsigned char)(p23 & 0xff);
        hb[rb + 48] = (unsigned char)((p23 >> 8) & 0xff);
      }
    }
  }
  // epilogue 2: fused scores (block holds all 128 channels of `head`)
  float asv[4], adv[4];
#pragma unroll
  for (int j = 0; j < 4; j++){
    int c = wc * 64 + j * 16 + l16;
    asv[j] = a_src_v[head * CC + c];
    adv[j] = a_dst_v[head * CC + c];
  }
  float ps[4][4], pd[4][4];
#pragma unroll
  for (int i = 0; i < 4; i++)
#pragma unroll
    for (int r = 0; r < 4; r++){
      float s = 0.f, d = 0.f;
#pragma unroll
      for (int j = 0; j < 4; j++){
        s = fmaf(acc[i][j][r], asv[j], s);
        d = fmaf(acc[i][j][r], adv[j], d);
      }
      ps[i][r] = s; pd[i][r] = d;
    }
#pragma unroll
  for (int off = 1; off < 16; off <<= 1)
#pragma unroll
    for (int i = 0; i < 4; i++)
#pragma unroll
      for (int r = 0; r < 4; r++){
        ps[i][r] += __shfl_xor(ps[i][r], off);
        pd[i][r] += __shfl_xor(pd[i][r], off);
      }
  if (l16 == 0){
#pragma unroll
    for (int i = 0; i < 4; i++)
#pragma unroll
      for (int r = 0; r < 4; r++){
        int rl = wr * 64 + i * 16 + q * 4 + r;
        sred[wc][rl][0] = ps[i][r];
        sred[wc][rl][1] = pd[i][r];
      }
  }
  __syncthreads();
  if (tid < 128){
    int row = rowBase + tid;
    if (row < NN){
      ssrc[row * HH + head] = sred[0][tid][0] + sred[1][tid][0];
      sdst[row * HH + head] = sred[0][tid][1] + sred[1][tid][1];
    }
  }
}

// ---------------- bucketed CSR build -----------------------------------------
__global__ __launch_bounds__(256) void bucket_scatter(const int* __restrict__ e0,
    const int* __restrict__ e1, const int* __restrict__ e2,
    int* __restrict__ gcur, unsigned* __restrict__ pairs){
  int v = blockIdx.y;
  const int* ei = (v == 0) ? e0 : ((v == 1) ? e1 : e2);
  __shared__ int cnt[NB];
  __shared__ int base[NB];
  int tid = threadIdx.x;
  for (int i = tid; i < NB; i += 256) cnt[i] = 0;
  __syncthreads();
  int estart = blockIdx.x * EPB;
  int eend = min(estart + EPB, EE);
  for (int e = estart + tid; e < eend; e += 256)
    atomicAdd(&cnt[ei[EE + e] >> 8], 1);
  __syncthreads();
  for (int i = tid; i < NB; i += 256){
    int c = cnt[i];
    base[i] = (c > 0) ? atomicAdd(&gcur[v * NB + i], c) : 0;
    cnt[i] = 0;
  }
  __syncthreads();
  for (int e = estart + tid; e < eend; e += 256){
    int s = ei[e], d = ei[EE + e];
    int b = d >> 8;
    int off = base[b] + atomicAdd(&cnt[b], 1);
    if (off < CAP)
      pairs[(size_t)(v * NB + b) * CAP + off] = ((unsigned)(d & 255) << 16) | (unsigned)s;
  }
}

__global__ __launch_bounds__(256) void bucket_scan(const int* __restrict__ gcur,
                                                   int* __restrict__ bbase){
  int v = blockIdx.x;
  __shared__ int wsum[4];
  int tid = threadIdx.x, lane = tid & 63, wv = tid >> 6;
  int val = 0;
  if (tid < NB) val = min(gcur[v * NB + tid], CAP) + min(SPB, NN - tid * SPB);
  int x = val;
#pragma unroll
  for (int off = 1; off < 64; off <<= 1){
    int t = __shfl_up(x, off);
    if (lane >= off) x += t;
  }
  if (lane == 63) wsum[wv] = x;
  __syncthreads();
  int pre = 0;
#pragma unroll
  for (int w = 0; w < 4; w++) if (w < wv) pre += wsum[w];
  if (tid < NB) bbase[v * NB + tid] = pre + x - val;
}

__global__ __launch_bounds__(256) void bucket_csr(const int* __restrict__ gcur,
    const int* __restrict__ bbase, const unsigned* __restrict__ pairs,
    int* __restrict__ rowptr_all, int* __restrict__ colx_all){
  int v = blockIdx.y, b = blockIdx.x;
  int* rowptr = rowptr_all + v * (NN + 1);
  int* colx = colx_all + (size_t)v * (EE + NN);
  __shared__ int hist[SPB];
  __shared__ int wsum[4];
  __shared__ int lcol[CAP + SPB];
  int tid = threadIdx.x, lane = tid & 63, wv = tid >> 6;
  int node0 = b << 8;
  int nvalid = min(SPB, NN - node0);
  int cnt = min(gcur[v * NB + b], CAP);
  int base = bbase[v * NB + b];
  const unsigned* pp = pairs + (size_t)(v * NB + b) * CAP;
  hist[tid] = (tid < nvalid) ? 1 : 0;   // self loop
  __syncthreads();
  for (int i = tid; i < cnt; i += 256)
    atomicAdd(&hist[pp[i] >> 16], 1);
  __syncthreads();
  int val = hist[tid];
  int x = val;
#pragma unroll
  for (int off = 1; off < 64; off <<= 1){
    int t = __shfl_up(x, off);
    if (lane >= off) x += t;
  }
  if (lane == 63) wsum[wv] = x;
  __syncthreads();
  int pre = 0;
#pragma unroll
  for (int w = 0; w < 4; w++) if (w < wv) pre += wsum[w];
  int excl = pre + x - val;
  __syncthreads();
  hist[tid] = excl + ((tid < nvalid) ? 1 : 0);   // cursor past self loop
  if (tid < nvalid){
    rowptr[node0 + tid] = base + excl;
    lcol[excl] = node0 + tid;                     // self loop first
  }
  __syncthreads();
  for (int i = tid; i < cnt; i += 256){
    unsigned p = pp[i];
    int pos = atomicAdd(&hist[p >> 16], 1);
    lcol[pos] = (int)(p & 0xffffu);
  }
  __syncthreads();
  int total = cnt + nvalid;
  for (int i = tid; i < total; i += 256) colx[base + i] = lcol[i];
  if (b == NB - 1 && tid == 0) rowptr[NN] = base + total;
}

// ---------------- per-dst softmax + aggregate (R6 structure, verbatim) -------
__global__ __launch_bounds__(256) void aggregate(const unsigned char* __restrict__ hb_all,
    const float* __restrict__ ssrc_all, const float* __restrict__ sdst_all,
    const int* __restrict__ rowptr_all, const int* __restrict__ colx_all,
    const float* __restrict__ bb, unsigned short* __restrict__ vout_all){
  int v = blockIdx.y;
  const unsigned char* hb = hb_all + (size_t)v * NN * HC;
  const float* ssrc = ssrc_all + (size_t)v * NN * HH;
  const float* sdst = sdst_all + (size_t)v * NN * HH;
  const int* rowptr = rowptr_all + v * (NN + 1);
  const int* colx = colx_all + (size_t)v * (EE + NN);

  int wave = threadIdx.x >> 6, lane = threadIdx.x & 63;
  int node = blockIdx.x * 4 + wave;
  int start = rowptr[node];
  int deg = rowptr[node + 1] - start;
  int myh = lane >> 4;
  float sdh = sdst[node * HH + myh];
  float acc[8] = {0.f, 0.f, 0.f, 0.f, 0.f, 0.f, 0.f, 0.f};
  float dsum = 0.f;

#define AGG_FMA(CH, CE) { \
    f32x2 p0 = __builtin_amdgcn_cvt_pk_f32_fp8(CH.x, false); \
    f32x2 p1 = __builtin_amdgcn_cvt_pk_f32_fp8(CH.x, true); \
    f32x2 p2 = __builtin_amdgcn_cvt_pk_f32_fp8(CH.y, false); \
    f32x2 p3 = __builtin_amdgcn_cvt_pk_f32_fp8(CH.y, true); \
    acc[0] = fmaf(CE, p0[0], acc[0]); \
    acc[1] = fmaf(CE, p0[1], acc[1]); \
    acc[2] = fmaf(CE, p1[0], acc[2]); \
    acc[3] = fmaf(CE, p1[1], acc[3]); \
    acc[4] = fmaf(CE, p2[0], acc[4]); \
    acc[5] = fmaf(CE, p2[1], acc[5]); \
    acc[6] = fmaf(CE, p3[0], acc[6]); \
    acc[7] = fmaf(CE, p3[1], acc[7]); }

  if (deg <= 64){
    int cpre = (lane < deg) ? colx[start + lane] : 0;
    uint2 h0, h1, h2, h3, h4, h5, h6, h7;
    float s0, s1, s2, s3, s4, s5, s6, s7;
#define AGG_PRO(HP, SP, P) { \
    int sp = __shfl(cpre, min(P, deg - 1)); \
    HP = *(const uint2*)&hb[(size_t)(unsigned)(sp * HC) + lane * 8]; \
    SP = ssrc[sp * HH + myh]; }
    AGG_PRO(h0, s0, 0) AGG_PRO(h1, s1, 1) AGG_PRO(h2, s2, 2) AGG_PRO(h3, s3, 3)
    AGG_PRO(h4, s4, 4) AGG_PRO(h5, s5, 5) AGG_PRO(h6, s6, 6) AGG_PRO(h7, s7, 7)
#undef AGG_PRO
#define AGG_STEP(HP, SP, P) { \
    float ce = __expf(lrelu(SP + sdh)); \
    dsum += ce; \
    uint2 ch = HP; \
    int ni = i + 8 + P; \
    if (ni < deg){ \
      int ns = __shfl(cpre, ni); \
      HP = *(const uint2*)&hb[(size_t)(unsigned)(ns * HC) + lane * 8]; \
      SP = ssrc[ns * HH + myh]; \
    } \
    AGG_FMA(ch, ce) }
    int i = 0;
    for (; i + 8 <= deg; i += 8){
      AGG_STEP(h0, s0, 0) AGG_STEP(h1, s1, 1) AGG_STEP(h2, s2, 2) AGG_STEP(h3, s3, 3)
      AGG_STEP(h4, s4, 4) AGG_STEP(h5, s5, 5) AGG_STEP(h6, s6, 6) AGG_STEP(h7, s7, 7)
    }
#undef AGG_STEP
    int rem = deg - i;
#define AGG_TAIL(HP, SP, P) if (rem > P){ \
    float ce = __expf(lrelu(SP + sdh)); \
    dsum += ce; \
    AGG_FMA(HP, ce) }
    AGG_TAIL(h0, s0, 0) AGG_TAIL(h1, s1, 1) AGG_TAIL(h2, s2, 2) AGG_TAIL(h3, s3, 3)
    AGG_TAIL(h4, s4, 4) AGG_TAIL(h5, s5, 5) AGG_TAIL(h6, s6, 6)
#undef AGG_TAIL
  } else {
    for (int i = 0; i < deg; i++){
      int src = colx[start + i];
      float sv = ssrc[src * HH + myh];
      float ce = __expf(lrelu(sv + sdh));
      dsum += ce;
      uint2 ch = *(const uint2*)&hb[(size_t)(unsigned)(src * HC) + lane * 8];
      AGG_FMA(ch, ce)
    }
  }
#undef AGG_FMA
  float rinv = 0.25f / fmaxf(dsum, 1e-16f);
#pragma unroll
  for (int j = 0; j < 8; j++) acc[j] *= rinv;
#pragma unroll
  for (int off = 16; off < 64; off <<= 1){
#pragma unroll
    for (int j = 0; j < 8; j++) acc[j] += __shfl_xor(acc[j], off);
  }
  if (lane < 16){
    const float* bv = bb + v * CC;
    unsigned short* voutv = vout_all + (size_t)v * NN * CC;
    int c0 = lane * 8;
    short8 o;
#pragma unroll
    for (int j = 0; j < 8; j++){
      float vv = acc[j] + bv[c0 + j];
      float e = vv > 0.f ? vv : (__expf(vv) - 1.f);
      o[j] = (short)f2bf(e);
    }
    *(short8*)&voutv[(size_t)node * CC + c0] = o;
  }
}

// ---------------- view fusion + classifier (persistent blocks) ---------------
__global__ __launch_bounds__(256) void fuse_classify(const unsigned short* __restrict__ vb,
    const float* __restrict__ fw, const float* __restrict__ fb,
    const float* __restrict__ w1, const float* __restrict__ b1,
    const float* __restrict__ w2, const float* __restrict__ b2,
    float* __restrict__ out){
  __shared__ float sw1[CC * 64];
  __shared__ float sfused[4][CC];
  int tid = threadIdx.x;
  for (int i = tid * 4; i < CC * 64; i += 1024)
    *(float4*)&sw1[i] = *(const float4*)&w1[i];
  __syncthreads();
  int wave = tid >> 6, lane = tid & 63;
  float fwa = fw[lane * 2], fwb = fw[lane * 2 + 1];
  float w2a = w2[lane * 2], w2b = w2[lane * 2 + 1];
  float b1l = b1[lane];
  for (int g = 0; g < 8; g++){
    int node = blockIdx.x * 32 + g * 4 + wave;
    if (node < NN){
      unsigned r0 = *(const unsigned*)&vb[(size_t)(0 * NN + node) * CC + lane * 2];
      unsigned r1 = *(const unsigned*)&vb[(size_t)(1 * NN + node) * CC + lane * 2];
      unsigned r2 = *(const unsigned*)&vb[(size_t)(2 * NN + node) * CC + lane * 2];
      float v0x = bf2f((short)(r0 & 0xffffu)), v0y = bf2f((short)(r0 >> 16));
      float v1x = bf2f((short)(r1 & 0xffffu)), v1y = bf2f((short)(r1 >> 16));
      float v2x = bf2f((short)(r2 & 0xffffu)), v2y = bf2f((short)(r2 >> 16));
      float s0 = wave_sum64(v0x * fwa + v0y * fwb) + fb[0];
      float s1 = wave_sum64(v1x * fwa + v1y * fwb) + fb[0];
      float s2 = wave_sum64(v2x * fwa + v2y * fwb) + fb[0];
      float mx = fmaxf(s0, fmaxf(s1, s2));
      float e0 = __expf(s0 - mx), e1 = __expf(s1 - mx), e2 = __expf(s2 - mx);
      float rs = 1.f / (e0 + e1 + e2);
      float w0 = e0 * rs, w1v = e1 * rs, w2v = e2 * rs;
      float f0 = w0 * v0x + w1v * v1x + w2v * v2x;
      float f1 = w0 * v0y + w1v * v1y + w2v * v2y;
      sfused[wave][lane * 2]     = f0;
      sfused[wave][lane * 2 + 1] = f1;
      if (lane < 3){
        float wv = (lane == 0) ? w0 : ((lane == 1) ? w1v : w2v);
        out[2 * NN + node * 3 + lane] = wv;
      }
      __builtin_amdgcn_s_waitcnt(0);   // drain wave-local LDS writes
      float hc = b1l;
#pragma unroll 8
      for (int c = 0; c < CC; c++)
        hc = fmaf(sfused[wave][c], sw1[c * 64 + lane], hc);
      hc = fmaxf(hc, 0.f);
      float l0 = wave_sum64(hc * w2a);
      float l1 = wave_sum64(hc * w2b);
      if (lane == 0){
        out[node * 2]     = l0 + b2[0];
        out[node * 2 + 1] = l1 + b2[1];
      }
    }
  }
}

// ---------------- launch -----------------------------------------------------
extern "C" void kernel_launch(void* const* d_in, const int* in_sizes, int n_in,
                              void* d_out, int out_size, void* d_ws, size_t ws_size,
                              hipStream_t stream){
  const float* x      = (const float*)d_in[0];
  const int*   e0     = (const int*)d_in[1];
  const int*   e1     = (const int*)d_in[2];
  const int*   e2     = (const int*)d_in[3];
  const float* W      = (const float*)d_in[4];
  const float* a_src  = (const float*)d_in[5];
  const float* a_dst  = (const float*)d_in[6];
  const float* bb     = (const float*)d_in[7];
  const float* fus_w  = (const float*)d_in[8];
  const float* fus_b  = (const float*)d_in[9];
  const float* cls_w1 = (const float*)d_in[10];
  const float* cls_b1 = (const float*)d_in[11];
  const float* cls_w2 = (const float*)d_in[12];
  const float* cls_b2 = (const float*)d_in[13];
  float* out = (float*)d_out;

  // workspace layout (~157 MB). pairs (early) and vout (late) alias.
  unsigned short* xb = (unsigned short*)d_ws;                   // NN*FIN bf16
  unsigned char* hb  = (unsigned char*)(xb + (size_t)NN * FIN); // VV*NN*HC fp8
  unsigned short* wp = (unsigned short*)(hb + (size_t)VV * NN * HC); // VV*FIN*HC bf16
  float* ssrc = (float*)(wp + (size_t)VV * FIN * HC);           // VV*NN*HH
  float* sdst = ssrc + (size_t)VV * NN * HH;                    // VV*NN*HH
  int* gcur   = (int*)(sdst + (size_t)VV * NN * HH);            // VV*NB
  int* bbase  = gcur + VV * NB;                                 // VV*NB
  int* rowptr = bbase + VV * NB;                                // VV*(NN+1)
  int* colx   = rowptr + VV * (NN + 1);                         // VV*(EE+NN)
  unsigned* pairs = (unsigned*)(colx + (size_t)VV * (EE + NN)); // VV*NB*CAP (early)
  unsigned short* voutb = (unsigned short*)pairs;               // VV*NN*CC bf16 (late)

  hipMemsetAsync(gcur, 0, (size_t)VV * NB * sizeof(int), stream);
  cast_x<<<12500, 256, 0, stream>>>(x, xb);
  prep_w_all<<<1536, 256, 0, stream>>>(W, wp);
  dim3 p1grid((EE + EPB - 1) / EPB, 3);   // 391 x 3
  bucket_scatter<<<p1grid, 256, 0, stream>>>(e0, e1, e2, gcur, pairs);
  bucket_scan<<<3, 256, 0, stream>>>(gcur, bbase);
  dim3 p2grid(NB, 3);
  bucket_csr<<<p2grid, 256, 0, stream>>>(gcur, bbase, pairs, rowptr, colx);

  dim3 ggrid(391, 4, 3);
  gemm_mfma_scores<<<ggrid, 256, 0, stream>>>(xb, wp, hb, a_src, a_dst, ssrc, sdst);
  dim3 agrid(12500, 3);
  aggregate<<<agrid, 256, 0, stream>>>(hb, ssrc, sdst, rowptr, colx, bb, voutb);
  fuse_classify<<<1563, 256, 0, stream>>>(voutb, fus_w, fus_b, cls_w1, cls_b1,
                                          cls_w2, cls_b2, out);
}